// Round 1
// baseline (1338.070 us; speedup 1.0000x reference)
//
#include <hip/hip_runtime.h>

#define BB 512
#define TT 2048
#define II 8
#define HH 128
#define OO 96

typedef __attribute__((ext_vector_type(8))) short bf16x8;
typedef __attribute__((ext_vector_type(4))) float f32x4;

__device__ __forceinline__ float fast_rcp(float x) { return __builtin_amdgcn_rcpf(x); }
__device__ __forceinline__ float sigmoid_fast(float x) { return fast_rcp(1.0f + __expf(-x)); }
__device__ __forceinline__ float tanh_fast(float x) {
    // 1 - 2/(1+exp(2x)); stable at both tails
    return 1.0f - 2.0f * fast_rcp(1.0f + __expf(2.0f * x));
}
__device__ __forceinline__ unsigned short f2bf(float f) {
    unsigned int u = __builtin_bit_cast(unsigned int, f);
    u += 0x7fffu + ((u >> 16) & 1u);   // RNE
    return (unsigned short)(u >> 16);
}
__device__ __forceinline__ float bf2f(unsigned short h) {
    unsigned int u = ((unsigned int)h) << 16;
    return __builtin_bit_cast(float, u);
}

// Block = 8 waves (512 thr), ONE batch row, full T scan. grid = 512 = 2 blocks/CU:
// two independent recurrences interleave per SIMD to hide the per-step latency chain.
// Wave w owns j-block [16w,16w+16). MFMA 16x16x32 bf16, K_ext=160:
//   A rows (plane = row&1): {h_hi, h_lo} x k=[h(128) | x(8) | 0pad(24)], replicated 8x over M.
//   gate = C[reg0] + C[reg1]  (bf16 hi/lo split compensation)
// LDS h-buffer: 2 x 2 planes x 160 bf16 (plane=320B, buf=640B), double-buffered.
__global__ __launch_bounds__(512, 4) void gru_kernel(
    const float* __restrict__ x,     // [B, T, I]
    const float* __restrict__ w_ih,  // [3H, I]
    const float* __restrict__ w_hh,  // [3H, H]
    const float* __restrict__ b_ih,  // [3H]
    const float* __restrict__ b_hh,  // [3H]
    const float* __restrict__ fc_w,  // [O, H]
    const float* __restrict__ fc_b,  // [O]
    float* __restrict__ out)         // [B, O]
{
    __shared__ __align__(16) char hbuf[2 * 640];
    __shared__ __align__(16) float hfin[HH];

    const int tid = threadIdx.x;
    const int wv  = tid >> 6;
    const int ln  = tid & 63;
    const int col = ln & 15;       // C col = j within tile
    const int g4  = ln >> 4;       // k-subblock of A/B fragment
    const int p   = col & 1;       // A plane: even rows hi, odd rows lo
    const int j   = 16 * wv + col;
    const int b0  = blockIdx.x;

    // ---- B fragments (weights -> bf16, weight-stationary) ----
    // B[k=(ln>>4)*8+i][n=ln&15]: lane loads 8 consecutive k from w_hh row (gate,j)
    auto ldfrag_hh = [&](int grow, int ks) {
        const float* rowp = w_hh + grow * HH + 32 * ks + g4 * 8;
        float4 u = *(const float4*)(rowp);
        float4 v = *(const float4*)(rowp + 4);
        bf16x8 f;
        f[0] = (short)f2bf(u.x); f[1] = (short)f2bf(u.y);
        f[2] = (short)f2bf(u.z); f[3] = (short)f2bf(u.w);
        f[4] = (short)f2bf(v.x); f[5] = (short)f2bf(v.y);
        f[6] = (short)f2bf(v.z); f[7] = (short)f2bf(v.w);
        return f;
    };
    auto ldfrag_ih = [&](int grow) {      // k-step 4: W_ih in k'=0..7, zeros above
        bf16x8 f = {0, 0, 0, 0, 0, 0, 0, 0};
        if (g4 == 0) {
            const float* rowp = w_ih + grow * II;
            float4 u = *(const float4*)(rowp);
            float4 v = *(const float4*)(rowp + 4);
            f[0] = (short)f2bf(u.x); f[1] = (short)f2bf(u.y);
            f[2] = (short)f2bf(u.z); f[3] = (short)f2bf(u.w);
            f[4] = (short)f2bf(v.x); f[5] = (short)f2bf(v.y);
            f[6] = (short)f2bf(v.z); f[7] = (short)f2bf(v.w);
        }
        return f;
    };

    bf16x8 bR[5], bZ[5], bN[4], bX;
#pragma unroll
    for (int ks = 0; ks < 4; ++ks) {
        bR[ks] = ldfrag_hh(j, ks);
        bZ[ks] = ldfrag_hh(HH + j, ks);
        bN[ks] = ldfrag_hh(2 * HH + j, ks);
    }
    bR[4] = ldfrag_ih(j);
    bZ[4] = ldfrag_ih(HH + j);
    bX    = ldfrag_ih(2 * HH + j);

    const float bias_r  = b_ih[j] + b_hh[j];
    const float bias_z  = b_ih[HH + j] + b_hh[HH + j];
    const float bias_nh = b_hh[2 * HH + j];   // inside r*(.)
    const float bias_nx = b_ih[2 * HH + j];   // outside

    // ---- zero LDS (h=0, pads=0 both buffers): 1280 B ----
    for (int i = tid; i < 320; i += 512) ((int*)hbuf)[i] = 0;
    __syncthreads();

    // ---- x staging: wave 7, lanes 0..7 (lane = i) ----
    const float* xr = x + (size_t)b0 * TT * II + ln;
    float xc1 = 0.f, xc2 = 0.f;
    if (wv == 7 && ln < 8) {
        float x0 = xr[0];
        xc1 = xr[II];          // x(t=1)
        xc2 = xr[2 * II];      // x(t=2)
        unsigned short xh = f2bf(x0);
        char* xw = hbuf + (128 + ln) * 2;  // buf0, plane0 (hi)
        *(unsigned short*)(xw)       = xh;
        *(unsigned short*)(xw + 320) = f2bf(x0 - bf2f(xh));   // plane1 (lo)
    }
    __syncthreads();

    const char* abase = hbuf + p * 320 + g4 * 16;
    char* hw = hbuf + j * 2;
    float h0 = 0.f;
    const f32x4 zf = {0.f, 0.f, 0.f, 0.f};

#define STEP(BUF, XVAL)                                                         \
    {                                                                           \
        const char* ab = abase + (BUF) * 640;                                   \
        bf16x8 a0 = *(const bf16x8*)(ab);                                       \
        bf16x8 a1 = *(const bf16x8*)(ab + 64);                                  \
        bf16x8 a2 = *(const bf16x8*)(ab + 128);                                 \
        bf16x8 a3 = *(const bf16x8*)(ab + 192);                                 \
        bf16x8 a4 = *(const bf16x8*)(ab + 256);                                 \
        f32x4 aR = zf, aZ = zf, aN = zf, aX = zf;                               \
        aR = __builtin_amdgcn_mfma_f32_16x16x32_bf16(a0, bR[0], aR, 0, 0, 0);   \
        aZ = __builtin_amdgcn_mfma_f32_16x16x32_bf16(a0, bZ[0], aZ, 0, 0, 0);   \
        aN = __builtin_amdgcn_mfma_f32_16x16x32_bf16(a0, bN[0], aN, 0, 0, 0);   \
        aR = __builtin_amdgcn_mfma_f32_16x16x32_bf16(a1, bR[1], aR, 0, 0, 0);   \
        aZ = __builtin_amdgcn_mfma_f32_16x16x32_bf16(a1, bZ[1], aZ, 0, 0, 0);   \
        aN = __builtin_amdgcn_mfma_f32_16x16x32_bf16(a1, bN[1], aN, 0, 0, 0);   \
        aR = __builtin_amdgcn_mfma_f32_16x16x32_bf16(a2, bR[2], aR, 0, 0, 0);   \
        aZ = __builtin_amdgcn_mfma_f32_16x16x32_bf16(a2, bZ[2], aZ, 0, 0, 0);   \
        aN = __builtin_amdgcn_mfma_f32_16x16x32_bf16(a2, bN[2], aN, 0, 0, 0);   \
        aR = __builtin_amdgcn_mfma_f32_16x16x32_bf16(a3, bR[3], aR, 0, 0, 0);   \
        aZ = __builtin_amdgcn_mfma_f32_16x16x32_bf16(a3, bZ[3], aZ, 0, 0, 0);   \
        aN = __builtin_amdgcn_mfma_f32_16x16x32_bf16(a3, bN[3], aN, 0, 0, 0);   \
        aR = __builtin_amdgcn_mfma_f32_16x16x32_bf16(a4, bR[4], aR, 0, 0, 0);   \
        aZ = __builtin_amdgcn_mfma_f32_16x16x32_bf16(a4, bZ[4], aZ, 0, 0, 0);   \
        aX = __builtin_amdgcn_mfma_f32_16x16x32_bf16(a4, bX,    aX, 0, 0, 0);   \
        float gr = aR[0] + aR[1] + bias_r;                                      \
        float gz = aZ[0] + aZ[1] + bias_z;                                      \
        float gn = aN[0] + aN[1] + bias_nh;                                     \
        float gx_ = aX[0] + aX[1] + bias_nx;                                    \
        float r0 = sigmoid_fast(gr);                                            \
        float z0 = sigmoid_fast(gz);                                            \
        float n0 = tanh_fast(fmaf(r0, gn, gx_));                                \
        h0 = fmaf(z0, h0 - n0, n0);                                             \
        if (ln < 16) {                                                          \
            char* w_ = hw + (1 - (BUF)) * 640;                                  \
            unsigned short s0 = f2bf(h0);                                       \
            *(unsigned short*)(w_)       = s0;                                  \
            *(unsigned short*)(w_ + 320) = f2bf(h0 - bf2f(s0));                 \
        }                                                                       \
        if (wv == 7 && ln < 8) {                                                \
            unsigned short xh = f2bf(XVAL);                                     \
            char* xw = hbuf + (1 - (BUF)) * 640 + (128 + ln) * 2;               \
            *(unsigned short*)(xw)       = xh;                                  \
            *(unsigned short*)(xw + 320) = f2bf((XVAL) - bf2f(xh));             \
        }                                                                       \
        __syncthreads();                                                        \
    }

    for (int it = 0; it < TT / 2; ++it) {
        float xn1 = 0.f, xn2 = 0.f;
        if (wv == 7 && ln < 8) {                      // prefetch x(t+3), x(t+4)
            int t3 = 2 * it + 3; if (t3 >= TT) t3 = TT - 1;
            int t4 = 2 * it + 4; if (t4 >= TT) t4 = TT - 1;
            xn1 = xr[t3 * II];
            xn2 = xr[t4 * II];
        }
        STEP(0, xc1)    // even t: read buf0, write buf1 (+ stage x(t+1))
        STEP(1, xc2)    // odd  t: read buf1, write buf0
        xc1 = xn1; xc2 = xn2;
    }
#undef STEP

    // ---- epilogue FC on fp32 h ----
    if (ln < 16) hfin[j] = h0;
    __syncthreads();

    if (tid < OO) {
        const float4* hf = (const float4*)(&hfin[0]);
        const float4* wp = (const float4*)(fc_w + tid * HH);
        float acc = fc_b[tid];
#pragma unroll 8
        for (int v = 0; v < HH / 4; ++v) {
            float4 w4 = wp[v];
            float4 h4 = hf[v];
            acc = fmaf(w4.x, h4.x, acc); acc = fmaf(w4.y, h4.y, acc);
            acc = fmaf(w4.z, h4.z, acc); acc = fmaf(w4.w, h4.w, acc);
        }
        out[(size_t)b0 * OO + tid] = acc;
    }
}

extern "C" void kernel_launch(void* const* d_in, const int* in_sizes, int n_in,
                              void* d_out, int out_size, void* d_ws, size_t ws_size,
                              hipStream_t stream) {
    const float* x    = (const float*)d_in[0];
    const float* w_ih = (const float*)d_in[1];
    const float* w_hh = (const float*)d_in[2];
    const float* b_ih = (const float*)d_in[3];
    const float* b_hh = (const float*)d_in[4];
    const float* fc_w = (const float*)d_in[5];
    const float* fc_b = (const float*)d_in[6];
    float* out = (float*)d_out;

    gru_kernel<<<BB, 512, 0, stream>>>(x, w_ih, w_hh, b_ih, b_hh, fc_w, fc_b, out);
}

// Round 2
// 996.868 us; speedup vs baseline: 1.3423x; 1.3423x over previous
//
#include <hip/hip_runtime.h>

#define BB 512
#define TT 2048
#define II 8
#define HH 128
#define OO 96

typedef __attribute__((ext_vector_type(8))) short bf16x8;
typedef __attribute__((ext_vector_type(4))) float f32x4;

__device__ __forceinline__ float fast_rcp(float x) { return __builtin_amdgcn_rcpf(x); }
__device__ __forceinline__ float sigmoid_fast(float x) { return fast_rcp(1.0f + __expf(-x)); }
__device__ __forceinline__ float tanh_fast(float x) {
    // 1 - 2/(1+exp(2x)); stable at both tails
    return 1.0f - 2.0f * fast_rcp(1.0f + __expf(2.0f * x));
}
__device__ __forceinline__ unsigned short f2bf(float f) {
    unsigned int u = __builtin_bit_cast(unsigned int, f);
    u += 0x7fffu + ((u >> 16) & 1u);   // RNE
    return (unsigned short)(u >> 16);
}
__device__ __forceinline__ float bf2f(unsigned short h) {
    unsigned int u = ((unsigned int)h) << 16;
    return __builtin_bit_cast(float, u);
}

__device__ __forceinline__ float dot8(const float w[8], float4 a, float4 b, float acc) {
    acc = fmaf(w[0], a.x, acc); acc = fmaf(w[1], a.y, acc);
    acc = fmaf(w[2], a.z, acc); acc = fmaf(w[3], a.w, acc);
    acc = fmaf(w[4], b.x, acc); acc = fmaf(w[5], b.y, acc);
    acc = fmaf(w[6], b.z, acc); acc = fmaf(w[7], b.w, acc);
    return acc;
}

// Block = 8 waves (512 thr), 2 batch rows, full T scan, grid=256 (1 block/CU).
// Wave w owns j-block [16w,16w+16). MFMA 16x16x32 bf16, K=128 (h only, x via VALU):
//   A-row pattern (m&7): {hi b0, lo b0, hi b0, lo b0, hi b1, lo b1, hi b1, lo b1} x2
//   -> lane regs: gate(b=g4&1) = C[0] + C[1]  (bf16 hi/lo split compensation)
//   -> ONE gate-set per lane (halved gate VALU vs the {hi0,hi1,lo0,lo1}x4 packing).
// x-part (I=8) computed per-lane in fp32 (24 fmaf, one step ahead, off critical path);
// removes the ks=4 MFMAs (15 -> 12 per wave-step, -20% MFMA issue).
// LDS: 2 bufs x 4 planes {hi0,lo0,hi1,lo1} x 320B stride (256B used), dbl-buffered.
__global__ __launch_bounds__(512, 2) void gru_kernel(
    const float* __restrict__ x,     // [B, T, I]
    const float* __restrict__ w_ih,  // [3H, I]
    const float* __restrict__ w_hh,  // [3H, H]
    const float* __restrict__ b_ih,  // [3H]
    const float* __restrict__ b_hh,  // [3H]
    const float* __restrict__ fc_w,  // [O, H]
    const float* __restrict__ fc_b,  // [O]
    float* __restrict__ out)         // [B, O]
{
    __shared__ __align__(16) char hbuf[2 * 1280];
    __shared__ __align__(16) float hfin[2][HH];

    const int tid = threadIdx.x;
    const int wv  = tid >> 6;
    const int ln  = tid & 63;
    const int col = ln & 15;       // C col = j within tile
    const int g4  = ln >> 4;       // k-subblock of A/B fragment
    const int b   = g4 & 1;        // this lane's batch row
    const int p   = ((ln >> 2) & 1) * 2 + (ln & 1);   // A plane for row=ln&15
    const int j   = 16 * wv + col;
    const int b0  = blockIdx.x * 2;

    // ---- B fragments (w_hh -> bf16, weight-stationary), K=128 ----
    // B[k=(ln>>4)*8+i][n=ln&15]: lane loads 8 consecutive k from w_hh row (gate,j)
    auto ldfrag_hh = [&](int grow, int ks) {
        const float* rowp = w_hh + grow * HH + 32 * ks + g4 * 8;
        float4 u = *(const float4*)(rowp);
        float4 v = *(const float4*)(rowp + 4);
        bf16x8 f;
        f[0] = (short)f2bf(u.x); f[1] = (short)f2bf(u.y);
        f[2] = (short)f2bf(u.z); f[3] = (short)f2bf(u.w);
        f[4] = (short)f2bf(v.x); f[5] = (short)f2bf(v.y);
        f[6] = (short)f2bf(v.z); f[7] = (short)f2bf(v.w);
        return f;
    };

    bf16x8 bR[4], bZ[4], bN[4];
#pragma unroll
    for (int ks = 0; ks < 4; ++ks) {
        bR[ks] = ldfrag_hh(j, ks);
        bZ[ks] = ldfrag_hh(HH + j, ks);
        bN[ks] = ldfrag_hh(2 * HH + j, ks);
    }

    // ---- w_ih rows in fp32 registers (per-lane x-dot weights) ----
    float wr[8], wz[8], wn[8];
    {
        float4 u, v;
        u = *(const float4*)(w_ih + j * II);            v = *(const float4*)(w_ih + j * II + 4);
        wr[0]=u.x; wr[1]=u.y; wr[2]=u.z; wr[3]=u.w; wr[4]=v.x; wr[5]=v.y; wr[6]=v.z; wr[7]=v.w;
        u = *(const float4*)(w_ih + (HH + j) * II);     v = *(const float4*)(w_ih + (HH + j) * II + 4);
        wz[0]=u.x; wz[1]=u.y; wz[2]=u.z; wz[3]=u.w; wz[4]=v.x; wz[5]=v.y; wz[6]=v.z; wz[7]=v.w;
        u = *(const float4*)(w_ih + (2 * HH + j) * II); v = *(const float4*)(w_ih + (2 * HH + j) * II + 4);
        wn[0]=u.x; wn[1]=u.y; wn[2]=u.z; wn[3]=u.w; wn[4]=v.x; wn[5]=v.y; wn[6]=v.z; wn[7]=v.w;
    }

    const float bias_r  = b_ih[j] + b_hh[j];
    const float bias_z  = b_ih[HH + j] + b_hh[HH + j];
    const float bias_nh = b_hh[2 * HH + j];   // inside r*(.)
    const float bias_nx = b_ih[2 * HH + j];   // outside

    // ---- zero LDS (h=0 both buffers) ----
    for (int i = tid; i < 640; i += 512) ((int*)hbuf)[i] = 0;
    __syncthreads();

    const char* abase = hbuf + p * 320 + g4 * 16;
    char* wbase = hbuf + b * 640 + (j << 1);          // + (1-RBUF)*1280 at use
    const float* xp = x + (size_t)(b0 + b) * TT * II;

    float h0 = 0.f;
    const f32x4 zf = {0.f, 0.f, 0.f, 0.f};

    // ---- prologue: gx for t=0,1 ----
    float gxr0, gxz0, gxn0, gxr1, gxz1, gxn1;
    {
        float4 xa = *(const float4*)(xp);          float4 xb = *(const float4*)(xp + 4);
        float4 xc = *(const float4*)(xp + II);     float4 xd = *(const float4*)(xp + II + 4);
        gxr0 = dot8(wr, xa, xb, bias_r);
        gxz0 = dot8(wz, xa, xb, bias_z);
        gxn0 = dot8(wn, xa, xb, bias_nx);
        gxr1 = dot8(wr, xc, xd, bias_r);
        gxz1 = dot8(wz, xc, xd, bias_z);
        gxn1 = dot8(wn, xc, xd, bias_nx);
    }

#define STEP(RBUF, GXR, GXZ, GXN)                                               \
    {                                                                           \
        const char* ab = abase + (RBUF) * 1280;                                 \
        bf16x8 a0 = *(const bf16x8*)(ab);                                       \
        bf16x8 a1 = *(const bf16x8*)(ab + 64);                                  \
        bf16x8 a2 = *(const bf16x8*)(ab + 128);                                 \
        bf16x8 a3 = *(const bf16x8*)(ab + 192);                                 \
        f32x4 aR = zf, aZ = zf, aN = zf;                                        \
        aR = __builtin_amdgcn_mfma_f32_16x16x32_bf16(a0, bR[0], aR, 0, 0, 0);   \
        aZ = __builtin_amdgcn_mfma_f32_16x16x32_bf16(a0, bZ[0], aZ, 0, 0, 0);   \
        aN = __builtin_amdgcn_mfma_f32_16x16x32_bf16(a0, bN[0], aN, 0, 0, 0);   \
        aR = __builtin_amdgcn_mfma_f32_16x16x32_bf16(a1, bR[1], aR, 0, 0, 0);   \
        aZ = __builtin_amdgcn_mfma_f32_16x16x32_bf16(a1, bZ[1], aZ, 0, 0, 0);   \
        aN = __builtin_amdgcn_mfma_f32_16x16x32_bf16(a1, bN[1], aN, 0, 0, 0);   \
        aR = __builtin_amdgcn_mfma_f32_16x16x32_bf16(a2, bR[2], aR, 0, 0, 0);   \
        aZ = __builtin_amdgcn_mfma_f32_16x16x32_bf16(a2, bZ[2], aZ, 0, 0, 0);   \
        aN = __builtin_amdgcn_mfma_f32_16x16x32_bf16(a2, bN[2], aN, 0, 0, 0);   \
        aR = __builtin_amdgcn_mfma_f32_16x16x32_bf16(a3, bR[3], aR, 0, 0, 0);   \
        aZ = __builtin_amdgcn_mfma_f32_16x16x32_bf16(a3, bZ[3], aZ, 0, 0, 0);   \
        aN = __builtin_amdgcn_mfma_f32_16x16x32_bf16(a3, bN[3], aN, 0, 0, 0);   \
        float gr = aR[0] + aR[1] + (GXR);                                       \
        float gz = aZ[0] + aZ[1] + (GXZ);                                       \
        float gn = aN[0] + aN[1] + bias_nh;                                     \
        float r0 = sigmoid_fast(gr);                                            \
        float z0 = sigmoid_fast(gz);                                            \
        float n0 = tanh_fast(fmaf(r0, gn, (GXN)));                              \
        h0 = fmaf(z0, h0 - n0, n0);                                             \
        if (ln < 32) {                                                          \
            char* w_ = wbase + (1 - (RBUF)) * 1280;                             \
            unsigned short s0 = f2bf(h0);                                       \
            *(unsigned short*)(w_)       = s0;                                  \
            *(unsigned short*)(w_ + 320) = f2bf(h0 - bf2f(s0));                 \
        }                                                                       \
        __syncthreads();                                                        \
    }

    for (int it = 0; it < TT / 2; ++it) {
        // prefetch x(t+2), x(t+3) -- consumed at bottom of this iteration
        int t2 = 2 * it + 2; if (t2 > TT - 1) t2 = TT - 1;
        int t3 = 2 * it + 3; if (t3 > TT - 1) t3 = TT - 1;
        float4 pa = *(const float4*)(xp + t2 * II);
        float4 pb = *(const float4*)(xp + t2 * II + 4);
        float4 pc = *(const float4*)(xp + t3 * II);
        float4 pd = *(const float4*)(xp + t3 * II + 4);

        STEP(0, gxr0, gxz0, gxn0)   // even t: read buf0, write buf1
        STEP(1, gxr1, gxz1, gxn1)   // odd  t: read buf1, write buf0

        // compute gx for next iteration (fills the post-barrier LDS-wait window)
        gxr0 = dot8(wr, pa, pb, bias_r);
        gxz0 = dot8(wz, pa, pb, bias_z);
        gxn0 = dot8(wn, pa, pb, bias_nx);
        gxr1 = dot8(wr, pc, pd, bias_r);
        gxz1 = dot8(wz, pc, pd, bias_z);
        gxn1 = dot8(wn, pc, pd, bias_nx);
    }
#undef STEP

    // ---- epilogue FC on fp32 h ----
    if (ln < 32) hfin[b][j] = h0;
    __syncthreads();

    if (tid < 2 * OO) {
        const int bb2 = (tid >= OO) ? 1 : 0;
        const int o   = tid - OO * bb2;
        const float4* hf = (const float4*)(&hfin[bb2][0]);
        const float4* wp = (const float4*)(fc_w + o * HH);
        float acc = fc_b[o];
#pragma unroll 8
        for (int v = 0; v < HH / 4; ++v) {
            float4 w4 = wp[v];
            float4 h4 = hf[v];
            acc = fmaf(w4.x, h4.x, acc); acc = fmaf(w4.y, h4.y, acc);
            acc = fmaf(w4.z, h4.z, acc); acc = fmaf(w4.w, h4.w, acc);
        }
        out[(size_t)(b0 + bb2) * OO + o] = acc;
    }
}

extern "C" void kernel_launch(void* const* d_in, const int* in_sizes, int n_in,
                              void* d_out, int out_size, void* d_ws, size_t ws_size,
                              hipStream_t stream) {
    const float* x    = (const float*)d_in[0];
    const float* w_ih = (const float*)d_in[1];
    const float* w_hh = (const float*)d_in[2];
    const float* b_ih = (const float*)d_in[3];
    const float* b_hh = (const float*)d_in[4];
    const float* fc_w = (const float*)d_in[5];
    const float* fc_b = (const float*)d_in[6];
    float* out = (float*)d_out;

    gru_kernel<<<BB / 2, 512, 0, stream>>>(x, w_ih, w_hh, b_ih, b_hh, fc_w, fc_b, out);
}